// Round 1
// baseline (1671.125 us; speedup 1.0000x reference)
//
#include <hip/hip_runtime.h>
#include <hip/hip_bf16.h>
#include <stdint.h>

typedef _Float16 f16x8 __attribute__((ext_vector_type(8)));
typedef _Float16 f16x2 __attribute__((ext_vector_type(2)));
typedef float f32x4 __attribute__((ext_vector_type(4)));

#define LDA 136
#define LDB 136

// ---------------- weight prep: f32 [i][o] 128x128 tile -> fp16 [o][i] ----------------
struct PrepDesc { const float* src; _Float16* dst; };
struct PrepArgs { PrepDesc d[33]; };

__global__ __launch_bounds__(256) void prep_weights(PrepArgs args) {
    __shared__ _Float16 lds[128 * 129];
    const PrepDesc de = args.d[blockIdx.x];
    int t = threadIdx.x;
    for (int q = 0; q < 64; ++q) {
        int li = t + q * 256;            // linear over src [i][o]
        int i = li >> 7, o = li & 127;
        lds[o * 129 + i] = (_Float16)de.src[li];
    }
    __syncthreads();
    for (int q = 0; q < 64; ++q) {
        int lo = t + q * 256;            // linear over dst [o][i]
        int o = lo >> 7, i = lo & 127;
        de.dst[lo] = lds[o * 129 + i];
    }
}

// ---------------- f32 -> fp16 convert (node features) ----------------
__global__ __launch_bounds__(256) void f32_to_f16(const float* __restrict__ in,
                                                  _Float16* __restrict__ out, int n4) {
    int i = blockIdx.x * 256 + threadIdx.x;
    if (i >= n4) return;
    float4 v = *((const float4*)in + i);
    f16x2 a, b;
    a[0] = (_Float16)v.x; a[1] = (_Float16)v.y;
    b[0] = (_Float16)v.z; b[1] = (_Float16)v.w;
    f16x2* o = (f16x2*)out + i * 2;
    o[0] = a; o[1] = b;
}

// ---------------- unified K=128 fp16 MFMA GEMM ----------------
// C[m, cb+col] = sum_k A[m,k] * Bt[cb+col, k]  (+ agg + bias, relu, fp16/f32 out)
// flags: 1 = relu, 2 = accumulate into outf
__global__ __launch_bounds__(256) void gemm128(
    const _Float16* __restrict__ A,    // [M][128] fp16
    const _Float16* __restrict__ Bt,   // [ncols_total][128] fp16 (pre-transposed)
    int M,
    const float* __restrict__ agg,     // optional [M][128]
    const float* __restrict__ bias,    // optional [128]
    float* __restrict__ outf,          // optional [M][128] f32
    _Float16* __restrict__ outh,       // optional [M][out_stride] fp16
    int out_stride, int flags)
{
    __shared__ _Float16 As[64 * LDA];
    __shared__ _Float16 Bs[128 * LDB];
    int tid = threadIdx.x;
    int m0 = blockIdx.x * 64;
    int cb = blockIdx.y * 128;
    const _Float16* Bblk = Bt + (size_t)cb * 128;

    // stage A tile (64 x 128)
    for (int q = 0; q < 4; ++q) {
        int li = tid + q * 256;            // 0..1023
        int r = li >> 4;
        int c = (li & 15) << 3;
        int gr = m0 + r; if (gr >= M) gr = M - 1;
        f16x8 v = *(const f16x8*)(A + (size_t)gr * 128 + c);
        *(f16x8*)(As + r * LDA + c) = v;
    }
    // stage B tile (128 cols x 128 k), already [o][i]
    for (int q = 0; q < 8; ++q) {
        int li = tid + q * 256;            // 0..2047
        int r = li >> 4;
        int c = (li & 15) << 3;
        f16x8 v = *(const f16x8*)(Bblk + (size_t)r * 128 + c);
        *(f16x8*)(Bs + r * LDB + c) = v;
    }
    __syncthreads();

    int wid = tid >> 6, lane = tid & 63;
    int wr = (wid >> 1) * 32;     // wave row base within 64
    int wc = (wid & 1) * 64;      // wave col base within 128
    int lm = lane & 15;
    int lk = (lane >> 4) * 8;

    f32x4 acc[2][4] = {};
    for (int ks = 0; ks < 4; ++ks) {
        f16x8 a[2], b[4];
        for (int mi = 0; mi < 2; ++mi)
            a[mi] = *(const f16x8*)(As + (wr + mi * 16 + lm) * LDA + ks * 32 + lk);
        for (int ni = 0; ni < 4; ++ni)
            b[ni] = *(const f16x8*)(Bs + (wc + ni * 16 + lm) * LDB + ks * 32 + lk);
        for (int mi = 0; mi < 2; ++mi)
            for (int ni = 0; ni < 4; ++ni)
                acc[mi][ni] = __builtin_amdgcn_mfma_f32_16x16x32_f16(a[mi], b[ni], acc[mi][ni], 0, 0, 0);
    }

    int rbase = (lane >> 4) * 4;
    for (int mi = 0; mi < 2; ++mi) {
        for (int j = 0; j < 4; ++j) {
            int gr = m0 + wr + mi * 16 + rbase + j;
            if (gr >= M) continue;
            for (int ni = 0; ni < 4; ++ni) {
                int col = wc + ni * 16 + lm;   // 0..127 within this col-block
                float v = acc[mi][ni][j];
                if (agg)  v += agg[(size_t)gr * 128 + col];
                if (bias) v += bias[col];
                if (flags & 1) v = fmaxf(v, 0.f);
                if (outh) {
                    outh[(size_t)gr * out_stride + cb + col] = (_Float16)v;
                } else {
                    float* p = outf + (size_t)gr * 128 + col;
                    if (flags & 2) *p += v; else *p = v;
                }
            }
        }
    }
}

// ---------------- edge scatter: agg[dst] += coef[rel] . node_proj[src] ----------------
__global__ __launch_bounds__(256) void edge_agg(
    const int* __restrict__ src, const int* __restrict__ dst, const int* __restrict__ rel,
    const float* __restrict__ coef,          // [R][4]
    const _Float16* __restrict__ np,         // [N][4][128]
    float* __restrict__ agg, int E)
{
    int e = (blockIdx.x << 2) | (threadIdx.x >> 6);
    if (e >= E) return;
    int lane = threadIdx.x & 63;
    int s = src[e], d = dst[e], r = rel[e];
    float c0 = coef[r * 4 + 0], c1 = coef[r * 4 + 1];
    float c2 = coef[r * 4 + 2], c3 = coef[r * 4 + 3];
    const uint32_t* base = (const uint32_t*)(np + (size_t)s * 512);
    uint32_t v0 = base[lane], v1 = base[64 + lane], v2 = base[128 + lane], v3 = base[192 + lane];
    f16x2 u0 = __builtin_bit_cast(f16x2, v0);
    f16x2 u1 = __builtin_bit_cast(f16x2, v1);
    f16x2 u2 = __builtin_bit_cast(f16x2, v2);
    f16x2 u3 = __builtin_bit_cast(f16x2, v3);
    float mlo = c0 * (float)u0[0] + c1 * (float)u1[0] + c2 * (float)u2[0] + c3 * (float)u3[0];
    float mhi = c0 * (float)u0[1] + c1 * (float)u1[1] + c2 * (float)u2[1] + c3 * (float)u3[1];
    float* ag = agg + (size_t)d * 128 + 2 * lane;
    atomicAdd(ag, mlo);
    atomicAdd(ag + 1, mhi);
}

// ---------------- host launch ----------------
extern "C" void kernel_launch(void* const* d_in, const int* in_sizes, int n_in,
                              void* d_out, int out_size, void* d_ws, size_t ws_size,
                              hipStream_t stream) {
    const int D = 128;
    const int M = in_sizes[0] / D;   // num nodes

    struct ViewIn {
        const int *src, *dst, *rel;
        const float *bases1, *coef1, *loopw1, *bias1;
        const float *bases2, *coef2, *loopw2, *bias2;
        int E;
    } V[3];
    int idx = 1;
    for (int v = 0; v < 3; ++v) {
        V[v].src    = (const int*)d_in[idx + 0];
        V[v].dst    = (const int*)d_in[idx + 1];
        V[v].rel    = (const int*)d_in[idx + 2];
        V[v].bases1 = (const float*)d_in[idx + 3];
        V[v].coef1  = (const float*)d_in[idx + 4];
        V[v].loopw1 = (const float*)d_in[idx + 5];
        V[v].bias1  = (const float*)d_in[idx + 6];
        V[v].bases2 = (const float*)d_in[idx + 7];
        V[v].coef2  = (const float*)d_in[idx + 8];
        V[v].loopw2 = (const float*)d_in[idx + 9];
        V[v].bias2  = (const float*)d_in[idx + 10];
        V[v].E      = in_sizes[idx + 0];
        idx += 11;
    }
    const float* fusion_w = (const float*)d_in[idx];
    const float* fusion_b = (const float*)d_in[idx + 1];

    // ---- workspace carve ----
    char* w = (char*)d_ws;
    _Float16* np_buf = (_Float16*)w;  w += (size_t)M * 512 * 2;   // [N][4][128]
    float*    agg    = (float*)w;     w += (size_t)M * 128 * 4;
    _Float16* nf16   = (_Float16*)w;  w += (size_t)M * 128 * 2;
    _Float16* h1     = (_Float16*)w;  w += (size_t)M * 128 * 2;
    _Float16* h2     = (_Float16*)w;  w += (size_t)M * 128 * 2;
    _Float16* wts    = (_Float16*)w;  // transposed fp16 weights

    // weight layout per view: b1T [512][128], lw1T [128][128], b2T [512][128], lw2T [128][128]
    _Float16 *b1T[3], *lw1T[3], *b2T[3], *lw2T[3], *fusT[3];
    for (int v = 0; v < 3; ++v) {
        _Float16* base = wts + (size_t)v * 163840;
        b1T[v]  = base;
        lw1T[v] = base + 65536;
        b2T[v]  = base + 65536 + 16384;
        lw2T[v] = base + 65536 + 16384 + 65536;
    }
    for (int v = 0; v < 3; ++v) fusT[v] = wts + 3 * 163840 + (size_t)v * 16384;

    // ---- prep descriptors: 33 transposed 128x128 tiles ----
    PrepArgs pa;
    int t = 0;
    for (int v = 0; v < 3; ++v) {
        for (int b = 0; b < 4; ++b) { pa.d[t].src = V[v].bases1 + (size_t)b * 16384; pa.d[t].dst = b1T[v] + (size_t)b * 16384; ++t; }
        pa.d[t].src = V[v].loopw1; pa.d[t].dst = lw1T[v]; ++t;
        for (int b = 0; b < 4; ++b) { pa.d[t].src = V[v].bases2 + (size_t)b * 16384; pa.d[t].dst = b2T[v] + (size_t)b * 16384; ++t; }
        pa.d[t].src = V[v].loopw2; pa.d[t].dst = lw2T[v]; ++t;
    }
    for (int v = 0; v < 3; ++v) { pa.d[t].src = fusion_w + (size_t)v * 16384; pa.d[t].dst = fusT[v]; ++t; }

    prep_weights<<<33, 256, 0, stream>>>(pa);

    int n4 = M * D / 4;
    f32_to_f16<<<(n4 + 255) / 256, 256, 0, stream>>>((const float*)d_in[0], nf16, n4);

    int gx = (M + 63) / 64;
    float* outF = (float*)d_out;

    for (int v = 0; v < 3; ++v) {
        int E = V[v].E;
        int eg = (E + 3) / 4;
        // ---- layer 1 ----
        gemm128<<<dim3(gx, 4), 256, 0, stream>>>(nf16, b1T[v], M, nullptr, nullptr, nullptr, np_buf, 512, 0);
        hipMemsetAsync(agg, 0, (size_t)M * 128 * 4, stream);
        edge_agg<<<eg, 256, 0, stream>>>(V[v].src, V[v].dst, V[v].rel, V[v].coef1, np_buf, agg, E);
        gemm128<<<dim3(gx, 1), 256, 0, stream>>>(nf16, lw1T[v], M, agg, V[v].bias1, nullptr, h1, 128, 1 /*relu*/);
        // ---- layer 2 ----
        gemm128<<<dim3(gx, 4), 256, 0, stream>>>(h1, b2T[v], M, nullptr, nullptr, nullptr, np_buf, 512, 0);
        hipMemsetAsync(agg, 0, (size_t)M * 128 * 4, stream);
        edge_agg<<<eg, 256, 0, stream>>>(V[v].src, V[v].dst, V[v].rel, V[v].coef2, np_buf, agg, E);
        gemm128<<<dim3(gx, 1), 256, 0, stream>>>(h1, lw2T[v], M, agg, V[v].bias2, nullptr, h2, 128, 0);
        // ---- fusion: d_out (+)= h2 @ fusion_w[vD:(v+1)D] (+ bias on first view) ----
        gemm128<<<dim3(gx, 1), 256, 0, stream>>>(h2, fusT[v], M,
                                                 nullptr, v == 0 ? fusion_b : nullptr,
                                                 outF, nullptr, 128, v == 0 ? 0 : 2);
    }
}

// Round 2
// 975.342 us; speedup vs baseline: 1.7134x; 1.7134x over previous
//
#include <hip/hip_runtime.h>
#include <hip/hip_bf16.h>
#include <stdint.h>

typedef _Float16 f16x8 __attribute__((ext_vector_type(8)));
typedef _Float16 f16x2 __attribute__((ext_vector_type(2)));
typedef float f32x4 __attribute__((ext_vector_type(4)));

#define LDA 136
#define LDB 136

// ---------------- weight prep: f32 [i][o] 128x128 tile -> fp16 [o][i] ----------------
struct PrepDesc { const float* src; _Float16* dst; };
struct PrepArgs { PrepDesc d[33]; };

__global__ __launch_bounds__(256) void prep_weights(PrepArgs args) {
    __shared__ _Float16 lds[128 * 129];
    const PrepDesc de = args.d[blockIdx.x];
    int t = threadIdx.x;
    for (int q = 0; q < 64; ++q) {
        int li = t + q * 256;            // linear over src [i][o]
        int i = li >> 7, o = li & 127;
        lds[o * 129 + i] = (_Float16)de.src[li];
    }
    __syncthreads();
    for (int q = 0; q < 64; ++q) {
        int lo = t + q * 256;            // linear over dst [o][i]
        int o = lo >> 7, i = lo & 127;
        de.dst[lo] = lds[o * 129 + i];
    }
}

// ---------------- f32 -> fp16 convert (node features) ----------------
__global__ __launch_bounds__(256) void f32_to_f16(const float* __restrict__ in,
                                                  _Float16* __restrict__ out, int n4) {
    int i = blockIdx.x * 256 + threadIdx.x;
    if (i >= n4) return;
    float4 v = *((const float4*)in + i);
    f16x2 a, b;
    a[0] = (_Float16)v.x; a[1] = (_Float16)v.y;
    b[0] = (_Float16)v.z; b[1] = (_Float16)v.w;
    f16x2* o = (f16x2*)out + i * 2;
    o[0] = a; o[1] = b;
}

// ---------------- unified K=128 fp16 MFMA GEMM ----------------
__global__ __launch_bounds__(256) void gemm128(
    const _Float16* __restrict__ A,    // [M][128] fp16
    const _Float16* __restrict__ Bt,   // [ncols_total][128] fp16 (pre-transposed)
    int M,
    const float* __restrict__ agg,     // optional [M][128]
    const float* __restrict__ bias,    // optional [128]
    float* __restrict__ outf,          // optional [M][128] f32
    _Float16* __restrict__ outh,       // optional [M][out_stride] fp16
    int out_stride, int flags)
{
    __shared__ _Float16 As[64 * LDA];
    __shared__ _Float16 Bs[128 * LDB];
    int tid = threadIdx.x;
    int m0 = blockIdx.x * 64;
    int cb = blockIdx.y * 128;
    const _Float16* Bblk = Bt + (size_t)cb * 128;

    for (int q = 0; q < 4; ++q) {
        int li = tid + q * 256;
        int r = li >> 4;
        int c = (li & 15) << 3;
        int gr = m0 + r; if (gr >= M) gr = M - 1;
        f16x8 v = *(const f16x8*)(A + (size_t)gr * 128 + c);
        *(f16x8*)(As + r * LDA + c) = v;
    }
    for (int q = 0; q < 8; ++q) {
        int li = tid + q * 256;
        int r = li >> 4;
        int c = (li & 15) << 3;
        f16x8 v = *(const f16x8*)(Bblk + (size_t)r * 128 + c);
        *(f16x8*)(Bs + r * LDB + c) = v;
    }
    __syncthreads();

    int wid = tid >> 6, lane = tid & 63;
    int wr = (wid >> 1) * 32;
    int wc = (wid & 1) * 64;
    int lm = lane & 15;
    int lk = (lane >> 4) * 8;

    f32x4 acc[2][4] = {};
    for (int ks = 0; ks < 4; ++ks) {
        f16x8 a[2], b[4];
        for (int mi = 0; mi < 2; ++mi)
            a[mi] = *(const f16x8*)(As + (wr + mi * 16 + lm) * LDA + ks * 32 + lk);
        for (int ni = 0; ni < 4; ++ni)
            b[ni] = *(const f16x8*)(Bs + (wc + ni * 16 + lm) * LDB + ks * 32 + lk);
        for (int mi = 0; mi < 2; ++mi)
            for (int ni = 0; ni < 4; ++ni)
                acc[mi][ni] = __builtin_amdgcn_mfma_f32_16x16x32_f16(a[mi], b[ni], acc[mi][ni], 0, 0, 0);
    }

    int rbase = (lane >> 4) * 4;
    for (int mi = 0; mi < 2; ++mi) {
        for (int j = 0; j < 4; ++j) {
            int gr = m0 + wr + mi * 16 + rbase + j;
            if (gr >= M) continue;
            for (int ni = 0; ni < 4; ++ni) {
                int col = wc + ni * 16 + lm;
                float v = acc[mi][ni][j];
                if (agg)  v += agg[(size_t)gr * 128 + col];
                if (bias) v += bias[col];
                if (flags & 1) v = fmaxf(v, 0.f);
                if (outh) {
                    outh[(size_t)gr * out_stride + cb + col] = (_Float16)v;
                } else {
                    float* p = outf + (size_t)gr * 128 + col;
                    if (flags & 2) *p += v; else *p = v;
                }
            }
        }
    }
}

// ---------------- CSR build ----------------
__global__ __launch_bounds__(256) void hist_kernel(const int* __restrict__ dst,
                                                   int* __restrict__ deg, int E) {
    for (int e = blockIdx.x * 256 + threadIdx.x; e < E; e += gridDim.x * 256)
        atomicAdd(&deg[dst[e]], 1);
}

__global__ __launch_bounds__(1024) void scan_kernel(const int* __restrict__ deg,
                                                    int* __restrict__ off, int n) {
    __shared__ int buf[1024];
    __shared__ int carry;
    int t = threadIdx.x;
    if (t == 0) carry = 0;
    __syncthreads();
    for (int base = 0; base < n; base += 1024) {
        int x = (base + t < n) ? deg[base + t] : 0;
        buf[t] = x;
        __syncthreads();
        for (int s = 1; s < 1024; s <<= 1) {
            int v = (t >= s) ? buf[t - s] : 0;
            __syncthreads();
            buf[t] += v;
            __syncthreads();
        }
        if (base + t < n) off[base + t] = carry + buf[t] - x;   // exclusive
        __syncthreads();
        if (t == 0) carry += buf[1023];
        __syncthreads();
    }
    if (t == 0) off[n] = carry;
}

__global__ __launch_bounds__(256) void scatter_kernel(
    const int* __restrict__ src, const int* __restrict__ dst, const int* __restrict__ rel,
    int* __restrict__ cur, int* __restrict__ packed, int E) {
    for (int e = blockIdx.x * 256 + threadIdx.x; e < E; e += gridDim.x * 256) {
        int pos = atomicAdd(&cur[dst[e]], 1);
        packed[pos] = src[e] | (rel[e] << 20);
    }
}

// ---------------- CSR aggregation: one wave per dst node ----------------
__global__ __launch_bounds__(256) void gather_reduce(
    const int* __restrict__ off, const int* __restrict__ packed,
    const float* __restrict__ coef,          // [R][4]
    const _Float16* __restrict__ np,         // [N][4][128]
    float* __restrict__ agg, int N)
{
    int node = (blockIdx.x << 2) | (threadIdx.x >> 6);
    if (node >= N) return;
    int lane = threadIdx.x & 63;
    int i = off[node], e1 = off[node + 1];
    float mlo = 0.f, mhi = 0.f;

    for (; i + 1 < e1; i += 2) {
        int pa = packed[i], pb = packed[i + 1];
        int sa = pa & 0xFFFFF, ra = pa >> 20;
        int sb = pb & 0xFFFFF, rb = pb >> 20;
        const uint32_t* ba = (const uint32_t*)(np + (size_t)sa * 512);
        const uint32_t* bb = (const uint32_t*)(np + (size_t)sb * 512);
        uint32_t a0 = ba[lane], a1 = ba[64 + lane], a2 = ba[128 + lane], a3 = ba[192 + lane];
        uint32_t b0 = bb[lane], b1 = bb[64 + lane], b2 = bb[128 + lane], b3 = bb[192 + lane];
        float ca0 = coef[ra * 4], ca1 = coef[ra * 4 + 1], ca2 = coef[ra * 4 + 2], ca3 = coef[ra * 4 + 3];
        float cb0 = coef[rb * 4], cb1 = coef[rb * 4 + 1], cb2 = coef[rb * 4 + 2], cb3 = coef[rb * 4 + 3];
        f16x2 u;
        u = __builtin_bit_cast(f16x2, a0); mlo += ca0 * (float)u[0]; mhi += ca0 * (float)u[1];
        u = __builtin_bit_cast(f16x2, a1); mlo += ca1 * (float)u[0]; mhi += ca1 * (float)u[1];
        u = __builtin_bit_cast(f16x2, a2); mlo += ca2 * (float)u[0]; mhi += ca2 * (float)u[1];
        u = __builtin_bit_cast(f16x2, a3); mlo += ca3 * (float)u[0]; mhi += ca3 * (float)u[1];
        u = __builtin_bit_cast(f16x2, b0); mlo += cb0 * (float)u[0]; mhi += cb0 * (float)u[1];
        u = __builtin_bit_cast(f16x2, b1); mlo += cb1 * (float)u[0]; mhi += cb1 * (float)u[1];
        u = __builtin_bit_cast(f16x2, b2); mlo += cb2 * (float)u[0]; mhi += cb2 * (float)u[1];
        u = __builtin_bit_cast(f16x2, b3); mlo += cb3 * (float)u[0]; mhi += cb3 * (float)u[1];
    }
    if (i < e1) {
        int pa = packed[i];
        int sa = pa & 0xFFFFF, ra = pa >> 20;
        const uint32_t* ba = (const uint32_t*)(np + (size_t)sa * 512);
        uint32_t a0 = ba[lane], a1 = ba[64 + lane], a2 = ba[128 + lane], a3 = ba[192 + lane];
        float ca0 = coef[ra * 4], ca1 = coef[ra * 4 + 1], ca2 = coef[ra * 4 + 2], ca3 = coef[ra * 4 + 3];
        f16x2 u;
        u = __builtin_bit_cast(f16x2, a0); mlo += ca0 * (float)u[0]; mhi += ca0 * (float)u[1];
        u = __builtin_bit_cast(f16x2, a1); mlo += ca1 * (float)u[0]; mhi += ca1 * (float)u[1];
        u = __builtin_bit_cast(f16x2, a2); mlo += ca2 * (float)u[0]; mhi += ca2 * (float)u[1];
        u = __builtin_bit_cast(f16x2, a3); mlo += ca3 * (float)u[0]; mhi += ca3 * (float)u[1];
    }
    float* ag = agg + (size_t)node * 128 + 2 * lane;
    ag[0] = mlo;
    ag[1] = mhi;
}

// ---------------- host launch ----------------
extern "C" void kernel_launch(void* const* d_in, const int* in_sizes, int n_in,
                              void* d_out, int out_size, void* d_ws, size_t ws_size,
                              hipStream_t stream) {
    const int D = 128;
    const int M = in_sizes[0] / D;   // num nodes

    struct ViewIn {
        const int *src, *dst, *rel;
        const float *bases1, *coef1, *loopw1, *bias1;
        const float *bases2, *coef2, *loopw2, *bias2;
        int E;
    } V[3];
    int idx = 1;
    for (int v = 0; v < 3; ++v) {
        V[v].src    = (const int*)d_in[idx + 0];
        V[v].dst    = (const int*)d_in[idx + 1];
        V[v].rel    = (const int*)d_in[idx + 2];
        V[v].bases1 = (const float*)d_in[idx + 3];
        V[v].coef1  = (const float*)d_in[idx + 4];
        V[v].loopw1 = (const float*)d_in[idx + 5];
        V[v].bias1  = (const float*)d_in[idx + 6];
        V[v].bases2 = (const float*)d_in[idx + 7];
        V[v].coef2  = (const float*)d_in[idx + 8];
        V[v].loopw2 = (const float*)d_in[idx + 9];
        V[v].bias2  = (const float*)d_in[idx + 10];
        V[v].E      = in_sizes[idx + 0];
        idx += 11;
    }
    const float* fusion_w = (const float*)d_in[idx];
    const float* fusion_b = (const float*)d_in[idx + 1];

    // ---- workspace carve ----
    char* w = (char*)d_ws;
    _Float16* np_buf = (_Float16*)w;  w += (size_t)M * 512 * 2;   // [N][4][128]
    float*    agg    = (float*)w;     w += (size_t)M * 128 * 4;
    _Float16* nf16   = (_Float16*)w;  w += (size_t)M * 128 * 2;
    _Float16* h1     = (_Float16*)w;  w += (size_t)M * 128 * 2;
    _Float16* h2     = (_Float16*)w;  w += (size_t)M * 128 * 2;
    _Float16* wts    = (_Float16*)w;  w += (3 * 163840 + 3 * 16384) * 2;
    w = (char*)(((uintptr_t)w + 255) & ~(uintptr_t)255);
    int* deg = (int*)w;               w += (size_t)M * 4;
    int* cur = (int*)w;               w += (size_t)M * 4;
    int* off[3]; int* packed[3];
    for (int v = 0; v < 3; ++v) { off[v] = (int*)w; w += (size_t)(M + 1) * 4; }
    for (int v = 0; v < 3; ++v) { packed[v] = (int*)w; w += (size_t)V[v].E * 4; }

    _Float16 *b1T[3], *lw1T[3], *b2T[3], *lw2T[3], *fusT[3];
    for (int v = 0; v < 3; ++v) {
        _Float16* base = wts + (size_t)v * 163840;
        b1T[v]  = base;
        lw1T[v] = base + 65536;
        b2T[v]  = base + 65536 + 16384;
        lw2T[v] = base + 65536 + 16384 + 65536;
    }
    for (int v = 0; v < 3; ++v) fusT[v] = wts + 3 * 163840 + (size_t)v * 16384;

    // ---- prep: weight transposes ----
    PrepArgs pa;
    int t = 0;
    for (int v = 0; v < 3; ++v) {
        for (int b = 0; b < 4; ++b) { pa.d[t].src = V[v].bases1 + (size_t)b * 16384; pa.d[t].dst = b1T[v] + (size_t)b * 16384; ++t; }
        pa.d[t].src = V[v].loopw1; pa.d[t].dst = lw1T[v]; ++t;
        for (int b = 0; b < 4; ++b) { pa.d[t].src = V[v].bases2 + (size_t)b * 16384; pa.d[t].dst = b2T[v] + (size_t)b * 16384; ++t; }
        pa.d[t].src = V[v].loopw2; pa.d[t].dst = lw2T[v]; ++t;
    }
    for (int v = 0; v < 3; ++v) { pa.d[t].src = fusion_w + (size_t)v * 16384; pa.d[t].dst = fusT[v]; ++t; }
    prep_weights<<<33, 256, 0, stream>>>(pa);

    int n4 = M * D / 4;
    f32_to_f16<<<(n4 + 255) / 256, 256, 0, stream>>>((const float*)d_in[0], nf16, n4);

    // ---- CSR build per view (reused across both layers) ----
    for (int v = 0; v < 3; ++v) {
        int E = V[v].E;
        hipMemsetAsync(deg, 0, (size_t)M * 4, stream);
        hist_kernel<<<2048, 256, 0, stream>>>(V[v].dst, deg, E);
        scan_kernel<<<1, 1024, 0, stream>>>(deg, off[v], M);
        hipMemcpyAsync(cur, off[v], (size_t)M * 4, hipMemcpyDeviceToDevice, stream);
        scatter_kernel<<<2048, 256, 0, stream>>>(V[v].src, V[v].dst, V[v].rel, cur, packed[v], E);
    }

    int gx = (M + 63) / 64;
    int ng = (M + 3) / 4;
    float* outF = (float*)d_out;

    for (int v = 0; v < 3; ++v) {
        // ---- layer 1 ----
        gemm128<<<dim3(gx, 4), 256, 0, stream>>>(nf16, b1T[v], M, nullptr, nullptr, nullptr, np_buf, 512, 0);
        gather_reduce<<<ng, 256, 0, stream>>>(off[v], packed[v], V[v].coef1, np_buf, agg, M);
        gemm128<<<dim3(gx, 1), 256, 0, stream>>>(nf16, lw1T[v], M, agg, V[v].bias1, nullptr, h1, 128, 1 /*relu*/);
        // ---- layer 2 ----
        gemm128<<<dim3(gx, 4), 256, 0, stream>>>(h1, b2T[v], M, nullptr, nullptr, nullptr, np_buf, 512, 0);
        gather_reduce<<<ng, 256, 0, stream>>>(off[v], packed[v], V[v].coef2, np_buf, agg, M);
        gemm128<<<dim3(gx, 1), 256, 0, stream>>>(h1, lw2T[v], M, agg, V[v].bias2, nullptr, h2, 128, 0);
        // ---- fusion ----
        gemm128<<<dim3(gx, 1), 256, 0, stream>>>(h2, fusT[v], M,
                                                 nullptr, v == 0 ? fusion_b : nullptr,
                                                 outF, nullptr, 128, v == 0 ? 0 : 2);
    }
}

// Round 3
// 744.735 us; speedup vs baseline: 2.2439x; 1.3097x over previous
//
#include <hip/hip_runtime.h>
#include <hip/hip_bf16.h>
#include <stdint.h>

typedef _Float16 f16x8 __attribute__((ext_vector_type(8)));
typedef _Float16 f16x2 __attribute__((ext_vector_type(2)));
typedef float f32x4 __attribute__((ext_vector_type(4)));

#define LDA 136
#define LDB 136

// ---------------- weight prep: f32 [i][o] 128x128 tile -> fp16 [o][i] ----------------
struct PrepDesc { const float* src; _Float16* dst; };
struct PrepArgs { PrepDesc d[33]; };

__global__ __launch_bounds__(256) void prep_weights(PrepArgs args) {
    __shared__ _Float16 lds[128 * 129];
    const PrepDesc de = args.d[blockIdx.x];
    int t = threadIdx.x;
    for (int q = 0; q < 64; ++q) {
        int li = t + q * 256;            // linear over src [i][o]
        int i = li >> 7, o = li & 127;
        lds[o * 129 + i] = (_Float16)de.src[li];
    }
    __syncthreads();
    for (int q = 0; q < 64; ++q) {
        int lo = t + q * 256;            // linear over dst [o][i]
        int o = lo >> 7, i = lo & 127;
        de.dst[lo] = lds[o * 129 + i];
    }
}

// ---------------- f32 -> fp16 convert (node features) ----------------
__global__ __launch_bounds__(256) void f32_to_f16(const float* __restrict__ in,
                                                  _Float16* __restrict__ out, int n4) {
    int i = blockIdx.x * 256 + threadIdx.x;
    if (i >= n4) return;
    float4 v = *((const float4*)in + i);
    f16x2 a, b;
    a[0] = (_Float16)v.x; a[1] = (_Float16)v.y;
    b[0] = (_Float16)v.z; b[1] = (_Float16)v.w;
    f16x2* o = (f16x2*)out + i * 2;
    o[0] = a; o[1] = b;
}

// ---------------- unified K=128 fp16 MFMA GEMM ----------------
__global__ __launch_bounds__(256) void gemm128(
    const _Float16* __restrict__ A,    // [M][128] fp16
    const _Float16* __restrict__ Bt,   // [ncols_total][128] fp16 (pre-transposed)
    int M,
    const float* __restrict__ agg,     // optional [M][128]
    const float* __restrict__ bias,    // optional [128]
    float* __restrict__ outf,          // optional [M][128] f32
    _Float16* __restrict__ outh,       // optional [M][out_stride] fp16
    int out_stride, int flags)
{
    __shared__ _Float16 As[64 * LDA];
    __shared__ _Float16 Bs[128 * LDB];
    int tid = threadIdx.x;
    int m0 = blockIdx.x * 64;
    int cb = blockIdx.y * 128;
    const _Float16* Bblk = Bt + (size_t)cb * 128;

    for (int q = 0; q < 4; ++q) {
        int li = tid + q * 256;
        int r = li >> 4;
        int c = (li & 15) << 3;
        int gr = m0 + r; if (gr >= M) gr = M - 1;
        f16x8 v = *(const f16x8*)(A + (size_t)gr * 128 + c);
        *(f16x8*)(As + r * LDA + c) = v;
    }
    for (int q = 0; q < 8; ++q) {
        int li = tid + q * 256;
        int r = li >> 4;
        int c = (li & 15) << 3;
        f16x8 v = *(const f16x8*)(Bblk + (size_t)r * 128 + c);
        *(f16x8*)(Bs + r * LDB + c) = v;
    }
    __syncthreads();

    int wid = tid >> 6, lane = tid & 63;
    int wr = (wid >> 1) * 32;
    int wc = (wid & 1) * 64;
    int lm = lane & 15;
    int lk = (lane >> 4) * 8;

    f32x4 acc[2][4] = {};
    for (int ks = 0; ks < 4; ++ks) {
        f16x8 a[2], b[4];
        for (int mi = 0; mi < 2; ++mi)
            a[mi] = *(const f16x8*)(As + (wr + mi * 16 + lm) * LDA + ks * 32 + lk);
        for (int ni = 0; ni < 4; ++ni)
            b[ni] = *(const f16x8*)(Bs + (wc + ni * 16 + lm) * LDB + ks * 32 + lk);
        for (int mi = 0; mi < 2; ++mi)
            for (int ni = 0; ni < 4; ++ni)
                acc[mi][ni] = __builtin_amdgcn_mfma_f32_16x16x32_f16(a[mi], b[ni], acc[mi][ni], 0, 0, 0);
    }

    int rbase = (lane >> 4) * 4;
    for (int mi = 0; mi < 2; ++mi) {
        for (int j = 0; j < 4; ++j) {
            int gr = m0 + wr + mi * 16 + rbase + j;
            if (gr >= M) continue;
            for (int ni = 0; ni < 4; ++ni) {
                int col = wc + ni * 16 + lm;
                float v = acc[mi][ni][j];
                if (agg)  v += agg[(size_t)gr * 128 + col];
                if (bias) v += bias[col];
                if (flags & 1) v = fmaxf(v, 0.f);
                if (outh) {
                    outh[(size_t)gr * out_stride + cb + col] = (_Float16)v;
                } else {
                    float* p = outf + (size_t)gr * 128 + col;
                    if (flags & 2) *p += v; else *p = v;
                }
            }
        }
    }
}

// ---------------- CSR build ----------------
__global__ __launch_bounds__(256) void hist_kernel(const int* __restrict__ dst,
                                                   int* __restrict__ deg, int E) {
    for (int e = blockIdx.x * 256 + threadIdx.x; e < E; e += gridDim.x * 256)
        atomicAdd(&deg[dst[e]], 1);
}

// hierarchical scan, stage 1: per-block (2048 elems) exclusive scan + block sum
__global__ __launch_bounds__(256) void scan1_kernel(const int* __restrict__ deg,
                                                    int* __restrict__ off,
                                                    int* __restrict__ bsum, int n) {
    __shared__ int s[256];
    int b = blockIdx.x, t = threadIdx.x;
    int base = b * 2048 + t * 8;
    int v[8]; int sum = 0;
    for (int j = 0; j < 8; ++j) {
        int x = (base + j < n) ? deg[base + j] : 0;
        v[j] = sum;                    // exclusive within thread
        sum += x;
    }
    s[t] = sum;
    __syncthreads();
    for (int st = 1; st < 256; st <<= 1) {
        int y = (t >= st) ? s[t - st] : 0;
        __syncthreads();
        s[t] += y;
        __syncthreads();
    }
    int texcl = t ? s[t - 1] : 0;
    if (t == 255) bsum[b] = s[255];
    for (int j = 0; j < 8; ++j)
        if (base + j < n) off[base + j] = texcl + v[j];
}

// stage 2: add block prefixes (nblocks <= 32, serial prefix is cheap) + off[n]=E
__global__ __launch_bounds__(256) void scan2_kernel(int* __restrict__ off,
                                                    const int* __restrict__ bsum,
                                                    int n, int E) {
    __shared__ int pref;
    int b = blockIdx.x, t = threadIdx.x;
    if (t == 0) { int p = 0; for (int j = 0; j < b; ++j) p += bsum[j]; pref = p; }
    __syncthreads();
    int p = pref;
    int base = b * 2048 + t * 8;
    for (int j = 0; j < 8; ++j)
        if (base + j < n) off[base + j] += p;
    if (b == 0 && t == 0) off[n] = E;
}

__global__ __launch_bounds__(256) void scatter_kernel(
    const int* __restrict__ src, const int* __restrict__ dst, const int* __restrict__ rel,
    int* __restrict__ cur, int* __restrict__ packed, int E) {
    for (int e = blockIdx.x * 256 + threadIdx.x; e < E; e += gridDim.x * 256) {
        int pos = atomicAdd(&cur[dst[e]], 1);
        packed[pos] = src[e] | (rel[e] << 20);
    }
}

// ---------------- CSR aggregation: one wave per dst node ----------------
// lane l owns basis b=l>>4, dims 8*(l&15)..+7; per edge: one uint4 load.
// basis combine deferred to after the loop (2x shfl_xor).
__global__ __launch_bounds__(256) void gather_reduce(
    const int* __restrict__ off, const int* __restrict__ packed,
    const float* __restrict__ coef,          // [R][4]
    const _Float16* __restrict__ np,         // [N][4][128]
    float* __restrict__ agg, int N)
{
    int node = (blockIdx.x << 2) | (threadIdx.x >> 6);
    if (node >= N) return;
    int lane = threadIdx.x & 63;
    int b = lane >> 4;
    int dg = lane & 15;
    int i = off[node], e1 = off[node + 1];
    float acc[8] = {};

    for (; i + 1 < e1; i += 2) {
        int p0 = packed[i], p1 = packed[i + 1];
        int s0 = p0 & 0xFFFFF, r0 = p0 >> 20;
        int s1 = p1 & 0xFFFFF, r1 = p1 >> 20;
        uint4 q0 = ((const uint4*)(np + (size_t)s0 * 512))[lane];
        uint4 q1 = ((const uint4*)(np + (size_t)s1 * 512))[lane];
        float c0 = coef[r0 * 4 + b];
        float c1 = coef[r1 * 4 + b];
        f16x2 u;
        u = __builtin_bit_cast(f16x2, q0.x); acc[0] += c0 * (float)u[0]; acc[1] += c0 * (float)u[1];
        u = __builtin_bit_cast(f16x2, q0.y); acc[2] += c0 * (float)u[0]; acc[3] += c0 * (float)u[1];
        u = __builtin_bit_cast(f16x2, q0.z); acc[4] += c0 * (float)u[0]; acc[5] += c0 * (float)u[1];
        u = __builtin_bit_cast(f16x2, q0.w); acc[6] += c0 * (float)u[0]; acc[7] += c0 * (float)u[1];
        u = __builtin_bit_cast(f16x2, q1.x); acc[0] += c1 * (float)u[0]; acc[1] += c1 * (float)u[1];
        u = __builtin_bit_cast(f16x2, q1.y); acc[2] += c1 * (float)u[0]; acc[3] += c1 * (float)u[1];
        u = __builtin_bit_cast(f16x2, q1.z); acc[4] += c1 * (float)u[0]; acc[5] += c1 * (float)u[1];
        u = __builtin_bit_cast(f16x2, q1.w); acc[6] += c1 * (float)u[0]; acc[7] += c1 * (float)u[1];
    }
    if (i < e1) {
        int p0 = packed[i];
        int s0 = p0 & 0xFFFFF, r0 = p0 >> 20;
        uint4 q0 = ((const uint4*)(np + (size_t)s0 * 512))[lane];
        float c0 = coef[r0 * 4 + b];
        f16x2 u;
        u = __builtin_bit_cast(f16x2, q0.x); acc[0] += c0 * (float)u[0]; acc[1] += c0 * (float)u[1];
        u = __builtin_bit_cast(f16x2, q0.y); acc[2] += c0 * (float)u[0]; acc[3] += c0 * (float)u[1];
        u = __builtin_bit_cast(f16x2, q0.z); acc[4] += c0 * (float)u[0]; acc[5] += c0 * (float)u[1];
        u = __builtin_bit_cast(f16x2, q0.w); acc[6] += c0 * (float)u[0]; acc[7] += c0 * (float)u[1];
    }
    // combine the 4 bases (lanes dg, dg+16, dg+32, dg+48)
    for (int j = 0; j < 8; ++j) {
        acc[j] += __shfl_xor(acc[j], 16);
        acc[j] += __shfl_xor(acc[j], 32);
    }
    if (b == 0) {
        float4* ag = (float4*)(agg + (size_t)node * 128 + 8 * dg);
        ag[0] = make_float4(acc[0], acc[1], acc[2], acc[3]);
        ag[1] = make_float4(acc[4], acc[5], acc[6], acc[7]);
    }
}

// ---------------- host launch ----------------
extern "C" void kernel_launch(void* const* d_in, const int* in_sizes, int n_in,
                              void* d_out, int out_size, void* d_ws, size_t ws_size,
                              hipStream_t stream) {
    const int D = 128;
    const int M = in_sizes[0] / D;   // num nodes

    struct ViewIn {
        const int *src, *dst, *rel;
        const float *bases1, *coef1, *loopw1, *bias1;
        const float *bases2, *coef2, *loopw2, *bias2;
        int E;
    } V[3];
    int idx = 1;
    for (int v = 0; v < 3; ++v) {
        V[v].src    = (const int*)d_in[idx + 0];
        V[v].dst    = (const int*)d_in[idx + 1];
        V[v].rel    = (const int*)d_in[idx + 2];
        V[v].bases1 = (const float*)d_in[idx + 3];
        V[v].coef1  = (const float*)d_in[idx + 4];
        V[v].loopw1 = (const float*)d_in[idx + 5];
        V[v].bias1  = (const float*)d_in[idx + 6];
        V[v].bases2 = (const float*)d_in[idx + 7];
        V[v].coef2  = (const float*)d_in[idx + 8];
        V[v].loopw2 = (const float*)d_in[idx + 9];
        V[v].bias2  = (const float*)d_in[idx + 10];
        V[v].E      = in_sizes[idx + 0];
        idx += 11;
    }
    const float* fusion_w = (const float*)d_in[idx];
    const float* fusion_b = (const float*)d_in[idx + 1];

    // ---- workspace carve ----
    char* w = (char*)d_ws;
    _Float16* np_buf = (_Float16*)w;  w += (size_t)M * 512 * 2;   // [N][4][128]
    float*    agg    = (float*)w;     w += (size_t)M * 128 * 4;
    _Float16* nf16   = (_Float16*)w;  w += (size_t)M * 128 * 2;
    _Float16* h1     = (_Float16*)w;  w += (size_t)M * 128 * 2;
    _Float16* h2     = (_Float16*)w;  w += (size_t)M * 128 * 2;
    _Float16* wts    = (_Float16*)w;  w += (3 * 163840 + 3 * 16384) * 2;
    w = (char*)(((uintptr_t)w + 255) & ~(uintptr_t)255);
    int* deg  = (int*)w;              w += (size_t)M * 4;
    int* cur  = (int*)w;              w += (size_t)M * 4;
    int* bsum = (int*)w;              w += 64 * 4;
    int* off[3]; int* packed[3];
    for (int v = 0; v < 3; ++v) { off[v] = (int*)w; w += (size_t)(M + 1) * 4; }
    for (int v = 0; v < 3; ++v) { packed[v] = (int*)w; w += (size_t)V[v].E * 4; }

    _Float16 *b1T[3], *lw1T[3], *b2T[3], *lw2T[3], *fusT[3];
    for (int v = 0; v < 3; ++v) {
        _Float16* base = wts + (size_t)v * 163840;
        b1T[v]  = base;
        lw1T[v] = base + 65536;
        b2T[v]  = base + 65536 + 16384;
        lw2T[v] = base + 65536 + 16384 + 65536;
    }
    for (int v = 0; v < 3; ++v) fusT[v] = wts + 3 * 163840 + (size_t)v * 16384;

    // ---- prep: weight transposes ----
    PrepArgs pa;
    int t = 0;
    for (int v = 0; v < 3; ++v) {
        for (int b = 0; b < 4; ++b) { pa.d[t].src = V[v].bases1 + (size_t)b * 16384; pa.d[t].dst = b1T[v] + (size_t)b * 16384; ++t; }
        pa.d[t].src = V[v].loopw1; pa.d[t].dst = lw1T[v]; ++t;
        for (int b = 0; b < 4; ++b) { pa.d[t].src = V[v].bases2 + (size_t)b * 16384; pa.d[t].dst = b2T[v] + (size_t)b * 16384; ++t; }
        pa.d[t].src = V[v].loopw2; pa.d[t].dst = lw2T[v]; ++t;
    }
    for (int v = 0; v < 3; ++v) { pa.d[t].src = fusion_w + (size_t)v * 16384; pa.d[t].dst = fusT[v]; ++t; }
    prep_weights<<<33, 256, 0, stream>>>(pa);

    int n4 = M * D / 4;
    f32_to_f16<<<(n4 + 255) / 256, 256, 0, stream>>>((const float*)d_in[0], nf16, n4);

    // ---- CSR build per view (reused across both layers) ----
    int nsb = (M + 2047) / 2048;
    for (int v = 0; v < 3; ++v) {
        int E = V[v].E;
        hipMemsetAsync(deg, 0, (size_t)M * 4, stream);
        hist_kernel<<<2048, 256, 0, stream>>>(V[v].dst, deg, E);
        scan1_kernel<<<nsb, 256, 0, stream>>>(deg, off[v], bsum, M);
        scan2_kernel<<<nsb, 256, 0, stream>>>(off[v], bsum, M, E);
        hipMemcpyAsync(cur, off[v], (size_t)M * 4, hipMemcpyDeviceToDevice, stream);
        scatter_kernel<<<2048, 256, 0, stream>>>(V[v].src, V[v].dst, V[v].rel, cur, packed[v], E);
    }

    int gx = (M + 63) / 64;
    int ng = (M + 3) / 4;
    float* outF = (float*)d_out;

    for (int v = 0; v < 3; ++v) {
        // ---- layer 1 ----
        gemm128<<<dim3(gx, 4), 256, 0, stream>>>(nf16, b1T[v], M, nullptr, nullptr, nullptr, np_buf, 512, 0);
        gather_reduce<<<ng, 256, 0, stream>>>(off[v], packed[v], V[v].coef1, np_buf, agg, M);
        gemm128<<<dim3(gx, 1), 256, 0, stream>>>(nf16, lw1T[v], M, agg, V[v].bias1, nullptr, h1, 128, 1 /*relu*/);
        // ---- layer 2 ----
        gemm128<<<dim3(gx, 4), 256, 0, stream>>>(h1, b2T[v], M, nullptr, nullptr, nullptr, np_buf, 512, 0);
        gather_reduce<<<ng, 256, 0, stream>>>(off[v], packed[v], V[v].coef2, np_buf, agg, M);
        gemm128<<<dim3(gx, 1), 256, 0, stream>>>(h1, lw2T[v], M, agg, V[v].bias2, nullptr, h2, 128, 0);
        // ---- fusion ----
        gemm128<<<dim3(gx, 1), 256, 0, stream>>>(h2, fusT[v], M,
                                                 nullptr, v == 0 ? fusion_b : nullptr,
                                                 outF, nullptr, 128, v == 0 ? 0 : 2);
    }
}

// Round 4
// 501.234 us; speedup vs baseline: 3.3340x; 1.4858x over previous
//
#include <hip/hip_runtime.h>
#include <hip/hip_bf16.h>
#include <stdint.h>

typedef _Float16 f16x8 __attribute__((ext_vector_type(8)));
typedef _Float16 f16x2 __attribute__((ext_vector_type(2)));
typedef float f32x4 __attribute__((ext_vector_type(4)));

#define LDA 136
#define LDB 136

// ------------- weight prep: f32 [i][o] 128x128 tile -> fp16 dst[o*stride + i] -------------
struct PrepDesc { const float* src; _Float16* dst; int dstride; };
struct PrepArgs { PrepDesc d[33]; };

__global__ __launch_bounds__(256) void prep_weights(PrepArgs args) {
    __shared__ _Float16 lds[128 * 129];
    const PrepDesc de = args.d[blockIdx.x];
    int t = threadIdx.x;
    for (int q = 0; q < 64; ++q) {
        int li = t + q * 256;            // linear over src [i][o]
        int i = li >> 7, o = li & 127;
        lds[o * 129 + i] = (_Float16)de.src[li];
    }
    __syncthreads();
    for (int q = 0; q < 64; ++q) {
        int lo = t + q * 256;            // linear over dst [o][i]
        int o = lo >> 7, i = lo & 127;
        de.dst[(size_t)o * de.dstride + i] = lds[o * 129 + i];
    }
}

// ---------------- f32 -> fp16 convert (node features) ----------------
__global__ __launch_bounds__(256) void f32_to_f16(const float* __restrict__ in,
                                                  _Float16* __restrict__ out, int n4) {
    int i = blockIdx.x * 256 + threadIdx.x;
    if (i >= n4) return;
    float4 v = *((const float4*)in + i);
    f16x2 a, b;
    a[0] = (_Float16)v.x; a[1] = (_Float16)v.y;
    b[0] = (_Float16)v.z; b[1] = (_Float16)v.w;
    f16x2* o = (f16x2*)out + i * 2;
    o[0] = a; o[1] = b;
}

// ---------------- CSR build ----------------
__global__ __launch_bounds__(256) void hist_kernel(const int* __restrict__ dst,
                                                   int* __restrict__ deg, int E) {
    for (int e = blockIdx.x * 256 + threadIdx.x; e < E; e += gridDim.x * 256)
        atomicAdd(&deg[dst[e]], 1);
}

__global__ __launch_bounds__(256) void scan1_kernel(const int* __restrict__ deg,
                                                    int* __restrict__ off,
                                                    int* __restrict__ bsum, int n) {
    __shared__ int s[256];
    int b = blockIdx.x, t = threadIdx.x;
    int base = b * 2048 + t * 8;
    int v[8]; int sum = 0;
    for (int j = 0; j < 8; ++j) {
        int x = (base + j < n) ? deg[base + j] : 0;
        v[j] = sum;
        sum += x;
    }
    s[t] = sum;
    __syncthreads();
    for (int st = 1; st < 256; st <<= 1) {
        int y = (t >= st) ? s[t - st] : 0;
        __syncthreads();
        s[t] += y;
        __syncthreads();
    }
    int texcl = t ? s[t - 1] : 0;
    if (t == 255) bsum[b] = s[255];
    for (int j = 0; j < 8; ++j)
        if (base + j < n) off[base + j] = texcl + v[j];
}

__global__ __launch_bounds__(256) void scan2_kernel(int* __restrict__ off,
                                                    int* __restrict__ cur,
                                                    const int* __restrict__ bsum,
                                                    int n, int E) {
    __shared__ int pref;
    int b = blockIdx.x, t = threadIdx.x;
    if (t == 0) { int p = 0; for (int j = 0; j < b; ++j) p += bsum[j]; pref = p; }
    __syncthreads();
    int p = pref;
    int base = b * 2048 + t * 8;
    for (int j = 0; j < 8; ++j)
        if (base + j < n) { int x = off[base + j] + p; off[base + j] = x; cur[base + j] = x; }
    if (b == 0 && t == 0) off[n] = E;
}

__global__ __launch_bounds__(256) void scatter_kernel(
    const int* __restrict__ src, const int* __restrict__ dst, const int* __restrict__ rel,
    int* __restrict__ cur, int* __restrict__ packed, int E) {
    for (int e = blockIdx.x * 256 + threadIdx.x; e < E; e += gridDim.x * 256) {
        int pos = atomicAdd(&cur[dst[e]], 1);
        packed[pos] = src[e] | (rel[e] << 20);
    }
}

// ---- gather_T: T[d][b][:] = sum_{e->d} coef[rel_e][b] * h[src_e][:]  (one wave/node) ----
// lane l owns dims (2l, 2l+1); per edge: ONE dword gather (wave reads 256B coalesced).
__global__ __launch_bounds__(256) void gather_T(
    const int* __restrict__ off, const int* __restrict__ packed,
    const float* __restrict__ coef,          // [R][4]
    const _Float16* __restrict__ h,          // [N][128]
    _Float16* __restrict__ T,                // [N][4][128]
    int N)
{
    int node = (blockIdx.x << 2) | (threadIdx.x >> 6);
    if (node >= N) return;
    int lane = threadIdx.x & 63;
    int i = off[node], e1 = off[node + 1];
    float acc[8] = {};   // [b][2]

    for (; i + 1 < e1; i += 2) {
        int p0 = packed[i], p1 = packed[i + 1];
        int s0 = p0 & 0xFFFFF, r0 = p0 >> 20;
        int s1 = p1 & 0xFFFFF, r1 = p1 >> 20;
        uint32_t q0 = ((const uint32_t*)(h + (size_t)s0 * 128))[lane];
        uint32_t q1 = ((const uint32_t*)(h + (size_t)s1 * 128))[lane];
        f16x2 u0 = __builtin_bit_cast(f16x2, q0);
        f16x2 u1 = __builtin_bit_cast(f16x2, q1);
        float lo0 = (float)u0[0], hi0 = (float)u0[1];
        float lo1 = (float)u1[0], hi1 = (float)u1[1];
        for (int b = 0; b < 4; ++b) {
            float c0 = coef[r0 * 4 + b];
            float c1 = coef[r1 * 4 + b];
            acc[2 * b]     += c0 * lo0 + c1 * lo1;
            acc[2 * b + 1] += c0 * hi0 + c1 * hi1;
        }
    }
    if (i < e1) {
        int p0 = packed[i];
        int s0 = p0 & 0xFFFFF, r0 = p0 >> 20;
        uint32_t q0 = ((const uint32_t*)(h + (size_t)s0 * 128))[lane];
        f16x2 u0 = __builtin_bit_cast(f16x2, q0);
        float lo0 = (float)u0[0], hi0 = (float)u0[1];
        for (int b = 0; b < 4; ++b) {
            float c0 = coef[r0 * 4 + b];
            acc[2 * b]     += c0 * lo0;
            acc[2 * b + 1] += c0 * hi0;
        }
    }
    _Float16* tb = T + (size_t)node * 512 + 2 * lane;
    for (int b = 0; b < 4; ++b) {
        f16x2 o; o[0] = (_Float16)acc[2 * b]; o[1] = (_Float16)acc[2 * b + 1];
        *(f16x2*)(tb + b * 128) = o;
    }
}

// ---- fused layer GEMM: out = [T | h] @ BT^T + bias (+relu), K = 640 ----
// BT: [128 out][640 k] fp16 (k = 4*128 bases-stacked, then 128 loopw)
__global__ __launch_bounds__(256) void gemm_fused(
    const _Float16* __restrict__ T,    // [M][512]
    const _Float16* __restrict__ h,    // [M][128]
    const _Float16* __restrict__ BT,   // [128][640]
    const float* __restrict__ bias,    // [128]
    _Float16* __restrict__ out,        // [M][128]
    int M, int relu)
{
    __shared__ _Float16 As[64 * LDA];
    __shared__ _Float16 Bs[128 * LDB];
    int tid = threadIdx.x;
    int m0 = blockIdx.x * 64;

    int wid = tid >> 6, lane = tid & 63;
    int wr = (wid >> 1) * 32;
    int wc = (wid & 1) * 64;
    int lm = lane & 15;
    int lk = (lane >> 4) * 8;

    f32x4 acc[2][4] = {};

    for (int kb = 0; kb < 5; ++kb) {
        // stage A 64x128 chunk
        const _Float16* Asrc; int astride;
        if (kb < 4) { Asrc = T + (size_t)kb * 128; astride = 512; }
        else        { Asrc = h;                    astride = 128; }
        for (int q = 0; q < 4; ++q) {
            int li = tid + q * 256;
            int r = li >> 4;
            int c = (li & 15) << 3;
            int gr = m0 + r; if (gr >= M) gr = M - 1;
            f16x8 v = *(const f16x8*)(Asrc + (size_t)gr * astride + c);
            *(f16x8*)(As + r * LDA + c) = v;
        }
        // stage B 128x128 chunk (row stride 640)
        for (int q = 0; q < 8; ++q) {
            int li = tid + q * 256;
            int r = li >> 4;
            int c = (li & 15) << 3;
            f16x8 v = *(const f16x8*)(BT + (size_t)r * 640 + kb * 128 + c);
            *(f16x8*)(Bs + r * LDB + c) = v;
        }
        __syncthreads();

        for (int ks = 0; ks < 4; ++ks) {
            f16x8 a[2], b[4];
            for (int mi = 0; mi < 2; ++mi)
                a[mi] = *(const f16x8*)(As + (wr + mi * 16 + lm) * LDA + ks * 32 + lk);
            for (int ni = 0; ni < 4; ++ni)
                b[ni] = *(const f16x8*)(Bs + (wc + ni * 16 + lm) * LDB + ks * 32 + lk);
            for (int mi = 0; mi < 2; ++mi)
                for (int ni = 0; ni < 4; ++ni)
                    acc[mi][ni] = __builtin_amdgcn_mfma_f32_16x16x32_f16(a[mi], b[ni], acc[mi][ni], 0, 0, 0);
        }
        __syncthreads();
    }

    int rbase = (lane >> 4) * 4;
    for (int mi = 0; mi < 2; ++mi) {
        for (int j = 0; j < 4; ++j) {
            int gr = m0 + wr + mi * 16 + rbase + j;
            if (gr >= M) continue;
            for (int ni = 0; ni < 4; ++ni) {
                int col = wc + ni * 16 + lm;
                float v = acc[mi][ni][j] + bias[col];
                if (relu) v = fmaxf(v, 0.f);
                out[(size_t)gr * 128 + col] = (_Float16)v;
            }
        }
    }
}

// ---------------- fusion GEMM (K=128, f32 accumulate into d_out) ----------------
__global__ __launch_bounds__(256) void gemm128(
    const _Float16* __restrict__ A,    // [M][128] fp16
    const _Float16* __restrict__ Bt,   // [128][128] fp16
    int M,
    const float* __restrict__ bias,    // optional [128]
    float* __restrict__ outf,          // [M][128] f32
    int accum)
{
    __shared__ _Float16 As[64 * LDA];
    __shared__ _Float16 Bs[128 * LDB];
    int tid = threadIdx.x;
    int m0 = blockIdx.x * 64;

    for (int q = 0; q < 4; ++q) {
        int li = tid + q * 256;
        int r = li >> 4;
        int c = (li & 15) << 3;
        int gr = m0 + r; if (gr >= M) gr = M - 1;
        f16x8 v = *(const f16x8*)(A + (size_t)gr * 128 + c);
        *(f16x8*)(As + r * LDA + c) = v;
    }
    for (int q = 0; q < 8; ++q) {
        int li = tid + q * 256;
        int r = li >> 4;
        int c = (li & 15) << 3;
        f16x8 v = *(const f16x8*)(Bt + (size_t)r * 128 + c);
        *(f16x8*)(Bs + r * LDB + c) = v;
    }
    __syncthreads();

    int wid = tid >> 6, lane = tid & 63;
    int wr = (wid >> 1) * 32;
    int wc = (wid & 1) * 64;
    int lm = lane & 15;
    int lk = (lane >> 4) * 8;

    f32x4 acc[2][4] = {};
    for (int ks = 0; ks < 4; ++ks) {
        f16x8 a[2], b[4];
        for (int mi = 0; mi < 2; ++mi)
            a[mi] = *(const f16x8*)(As + (wr + mi * 16 + lm) * LDA + ks * 32 + lk);
        for (int ni = 0; ni < 4; ++ni)
            b[ni] = *(const f16x8*)(Bs + (wc + ni * 16 + lm) * LDB + ks * 32 + lk);
        for (int mi = 0; mi < 2; ++mi)
            for (int ni = 0; ni < 4; ++ni)
                acc[mi][ni] = __builtin_amdgcn_mfma_f32_16x16x32_f16(a[mi], b[ni], acc[mi][ni], 0, 0, 0);
    }

    int rbase = (lane >> 4) * 4;
    for (int mi = 0; mi < 2; ++mi) {
        for (int j = 0; j < 4; ++j) {
            int gr = m0 + wr + mi * 16 + rbase + j;
            if (gr >= M) continue;
            for (int ni = 0; ni < 4; ++ni) {
                int col = wc + ni * 16 + lm;
                float v = acc[mi][ni][j];
                if (bias) v += bias[col];
                float* p = outf + (size_t)gr * 128 + col;
                if (accum) *p += v; else *p = v;
            }
        }
    }
}

// ---------------- host launch ----------------
extern "C" void kernel_launch(void* const* d_in, const int* in_sizes, int n_in,
                              void* d_out, int out_size, void* d_ws, size_t ws_size,
                              hipStream_t stream) {
    const int D = 128;
    const int M = in_sizes[0] / D;

    struct ViewIn {
        const int *src, *dst, *rel;
        const float *bases1, *coef1, *loopw1, *bias1;
        const float *bases2, *coef2, *loopw2, *bias2;
        int E;
    } V[3];
    int idx = 1;
    for (int v = 0; v < 3; ++v) {
        V[v].src    = (const int*)d_in[idx + 0];
        V[v].dst    = (const int*)d_in[idx + 1];
        V[v].rel    = (const int*)d_in[idx + 2];
        V[v].bases1 = (const float*)d_in[idx + 3];
        V[v].coef1  = (const float*)d_in[idx + 4];
        V[v].loopw1 = (const float*)d_in[idx + 5];
        V[v].bias1  = (const float*)d_in[idx + 6];
        V[v].bases2 = (const float*)d_in[idx + 7];
        V[v].coef2  = (const float*)d_in[idx + 8];
        V[v].loopw2 = (const float*)d_in[idx + 9];
        V[v].bias2  = (const float*)d_in[idx + 10];
        V[v].E      = in_sizes[idx + 0];
        idx += 11;
    }
    const float* fusion_w = (const float*)d_in[idx];
    const float* fusion_b = (const float*)d_in[idx + 1];

    // ---- workspace carve ----
    char* w = (char*)d_ws;
    _Float16* T    = (_Float16*)w;  w += (size_t)M * 512 * 2;   // [N][4][128]
    _Float16* nf16 = (_Float16*)w;  w += (size_t)M * 128 * 2;
    _Float16* h1   = (_Float16*)w;  w += (size_t)M * 128 * 2;
    _Float16* h2   = (_Float16*)w;  w += (size_t)M * 128 * 2;
    _Float16* wts  = (_Float16*)w;  w += (size_t)(6 * 81920 + 3 * 16384) * 2;
    w = (char*)(((uintptr_t)w + 255) & ~(uintptr_t)255);
    int* deg  = (int*)w;            w += (size_t)M * 4;
    int* cur  = (int*)w;            w += (size_t)M * 4;
    int* bsum = (int*)w;            w += 64 * 4;
    int* off[3]; int* packed[3];
    for (int v = 0; v < 3; ++v) { off[v] = (int*)w; w += (size_t)(M + 1) * 4; }
    for (int v = 0; v < 3; ++v) { packed[v] = (int*)w; w += (size_t)V[v].E * 4; }

    // WT[v][l]: [128][640] fp16 (4 bases + loopw); fusT[v]: [128][128]
    _Float16 *WT[3][2], *fusT[3];
    for (int v = 0; v < 3; ++v)
        for (int l = 0; l < 2; ++l)
            WT[v][l] = wts + (size_t)(v * 2 + l) * 81920;
    for (int v = 0; v < 3; ++v) fusT[v] = wts + 6 * 81920 + (size_t)v * 16384;

    // ---- prep descriptors ----
    PrepArgs pa;
    int t = 0;
    for (int v = 0; v < 3; ++v) {
        const float* bases[2] = { V[v].bases1, V[v].bases2 };
        const float* loopw[2] = { V[v].loopw1, V[v].loopw2 };
        for (int l = 0; l < 2; ++l) {
            for (int b = 0; b < 4; ++b) {
                pa.d[t].src = bases[l] + (size_t)b * 16384;
                pa.d[t].dst = WT[v][l] + (size_t)b * 128;
                pa.d[t].dstride = 640; ++t;
            }
            pa.d[t].src = loopw[l];
            pa.d[t].dst = WT[v][l] + 512;
            pa.d[t].dstride = 640; ++t;
        }
    }
    for (int v = 0; v < 3; ++v) {
        pa.d[t].src = fusion_w + (size_t)v * 16384;
        pa.d[t].dst = fusT[v];
        pa.d[t].dstride = 128; ++t;
    }
    prep_weights<<<33, 256, 0, stream>>>(pa);

    int n4 = M * D / 4;
    f32_to_f16<<<(n4 + 255) / 256, 256, 0, stream>>>((const float*)d_in[0], nf16, n4);

    // ---- CSR build per view ----
    int nsb = (M + 2047) / 2048;
    for (int v = 0; v < 3; ++v) {
        int E = V[v].E;
        hipMemsetAsync(deg, 0, (size_t)M * 4, stream);
        hist_kernel<<<1024, 256, 0, stream>>>(V[v].dst, deg, E);
        scan1_kernel<<<nsb, 256, 0, stream>>>(deg, off[v], bsum, M);
        scan2_kernel<<<nsb, 256, 0, stream>>>(off[v], cur, bsum, M, E);
        scatter_kernel<<<1024, 256, 0, stream>>>(V[v].src, V[v].dst, V[v].rel, cur, packed[v], E);
    }

    int gx = (M + 63) / 64;
    int ng = (M + 3) / 4;
    float* outF = (float*)d_out;

    for (int v = 0; v < 3; ++v) {
        // ---- layer 1 ----
        gather_T<<<ng, 256, 0, stream>>>(off[v], packed[v], V[v].coef1, nf16, T, M);
        gemm_fused<<<gx, 256, 0, stream>>>(T, nf16, WT[v][0], V[v].bias1, h1, M, 1);
        // ---- layer 2 ----
        gather_T<<<ng, 256, 0, stream>>>(off[v], packed[v], V[v].coef2, h1, T, M);
        gemm_fused<<<gx, 256, 0, stream>>>(T, h1, WT[v][1], V[v].bias2, h2, M, 0);
        // ---- fusion ----
        gemm128<<<gx, 256, 0, stream>>>(h2, fusT[v], M, v == 0 ? fusion_b : nullptr,
                                        outF, v == 0 ? 0 : 1);
    }
}

// Round 5
// 385.814 us; speedup vs baseline: 4.3314x; 1.2992x over previous
//
#include <hip/hip_runtime.h>
#include <hip/hip_bf16.h>
#include <stdint.h>

typedef _Float16 f16x8 __attribute__((ext_vector_type(8)));
typedef _Float16 f16x2 __attribute__((ext_vector_type(2)));
typedef float f32x4 __attribute__((ext_vector_type(4)));

#define AL 136   // LDS leading dim for 128-wide fp16 tiles (+8 pad)

// ------------- weight prep: f32 [i][o] 128x128 tile -> fp16 dst[o*stride + i] -------------
struct PrepDesc { const float* src; _Float16* dst; int dstride; };
struct PrepArgs { PrepDesc d[33]; };

__global__ __launch_bounds__(256) void prep_weights(PrepArgs args) {
    __shared__ _Float16 lds[128 * 129];
    const PrepDesc de = args.d[blockIdx.x];
    int t = threadIdx.x;
    for (int q = 0; q < 64; ++q) {
        int li = t + q * 256;            // linear over src [i][o]
        int i = li >> 7, o = li & 127;
        lds[o * 129 + i] = (_Float16)de.src[li];
    }
    __syncthreads();
    for (int q = 0; q < 64; ++q) {
        int lo = t + q * 256;            // linear over dst [o][i]
        int o = lo >> 7, i = lo & 127;
        de.dst[(size_t)o * de.dstride + i] = lds[o * 129 + i];
    }
}

// ---------------- f32 -> fp16 convert ----------------
__global__ __launch_bounds__(256) void f32_to_f16(const float* __restrict__ in,
                                                  _Float16* __restrict__ out, int n4) {
    int i = blockIdx.x * 256 + threadIdx.x;
    if (i >= n4) return;
    float4 v = *((const float4*)in + i);
    f16x2 a, b;
    a[0] = (_Float16)v.x; a[1] = (_Float16)v.y;
    b[0] = (_Float16)v.z; b[1] = (_Float16)v.w;
    f16x2* o = (f16x2*)out + i * 2;
    o[0] = a; o[1] = b;
}

// ---------------- CSR build (3 views concatenated: index space [3][N]) ----------------
struct EdgeArgs {
    const int* src[3]; const int* dst[3]; const int* rel[3];
    int E[3]; int N;
};

__global__ __launch_bounds__(256) void zero_deg(int* __restrict__ deg3, int n) {
    int i = blockIdx.x * 256 + threadIdx.x;
    if (i < n) deg3[i] = 0;
}

__global__ __launch_bounds__(256) void hist3(EdgeArgs ea, int* __restrict__ deg3) {
    int v = blockIdx.y;
    const int* dst = ea.dst[v];
    int* deg = deg3 + (size_t)v * ea.N;
    for (int e = blockIdx.x * 256 + threadIdx.x; e < ea.E[v]; e += gridDim.x * 256)
        atomicAdd(&deg[dst[e]], 1);
}

__global__ __launch_bounds__(256) void scan1_kernel(const int* __restrict__ deg,
                                                    int* __restrict__ off,
                                                    int* __restrict__ bsum, int n) {
    __shared__ int s[256];
    int b = blockIdx.x, t = threadIdx.x;
    int base = b * 2048 + t * 8;
    int v[8]; int sum = 0;
    for (int j = 0; j < 8; ++j) {
        int x = (base + j < n) ? deg[base + j] : 0;
        v[j] = sum;
        sum += x;
    }
    s[t] = sum;
    __syncthreads();
    for (int st = 1; st < 256; st <<= 1) {
        int y = (t >= st) ? s[t - st] : 0;
        __syncthreads();
        s[t] += y;
        __syncthreads();
    }
    int texcl = t ? s[t - 1] : 0;
    if (t == 255) bsum[b] = s[255];
    for (int j = 0; j < 8; ++j)
        if (base + j < n) off[base + j] = texcl + v[j];
}

__global__ __launch_bounds__(256) void scan2_kernel(int* __restrict__ off,
                                                    int* __restrict__ cur,
                                                    const int* __restrict__ bsum,
                                                    int n, int Etot) {
    __shared__ int pref;
    int b = blockIdx.x, t = threadIdx.x;
    if (t == 0) { int p = 0; for (int j = 0; j < b; ++j) p += bsum[j]; pref = p; }
    __syncthreads();
    int p = pref;
    int base = b * 2048 + t * 8;
    for (int j = 0; j < 8; ++j)
        if (base + j < n) { int x = off[base + j] + p; off[base + j] = x; cur[base + j] = x; }
    if (b == 0 && t == 0) off[n] = Etot;
}

__global__ __launch_bounds__(256) void scatter3(EdgeArgs ea, int* __restrict__ cur3,
                                                int* __restrict__ packed3) {
    int v = blockIdx.y;
    const int* src = ea.src[v];
    const int* dst = ea.dst[v];
    const int* rel = ea.rel[v];
    int* cur = cur3 + (size_t)v * ea.N;
    for (int e = blockIdx.x * 256 + threadIdx.x; e < ea.E[v]; e += gridDim.x * 256) {
        int pos = atomicAdd(&cur[dst[e]], 1);
        packed3[pos] = src[e] | (rel[e] << 20);
    }
}

// ---- gather: T[v][d][b][:] = sum_{e->d} coef_v[rel_e][b] * h_v[src_e][:], one wave/node ----
struct GatherArgs {
    const int* off3;          // per-view base already folded in for fallback; batched: +v*N
    const int* packed3;       // global edge records
    const float* coef[3];     // [R][4]
    const _Float16* h[3];     // [N][128] per-view input
    _Float16* T;              // output base
    int N; size_t Tvs;        // per-view stride into T (elements)
};

__global__ __launch_bounds__(256) void gather3(GatherArgs g) {
    int v = blockIdx.y;
    int node = (blockIdx.x << 2) | (threadIdx.x >> 6);
    if (node >= g.N) return;
    int lane = threadIdx.x & 63;
    const int* off = g.off3 + (size_t)v * g.N;
    const float* coef = g.coef[v];
    const _Float16* h = g.h[v];
    _Float16* T = g.T + (size_t)v * g.Tvs;

    int i = off[node], e1 = off[node + 1];
    float acc[8] = {};   // [b][2]

    for (; i + 1 < e1; i += 2) {
        int p0 = g.packed3[i], p1 = g.packed3[i + 1];
        int s0 = p0 & 0xFFFFF, r0 = p0 >> 20;
        int s1 = p1 & 0xFFFFF, r1 = p1 >> 20;
        uint32_t q0 = ((const uint32_t*)(h + (size_t)s0 * 128))[lane];
        uint32_t q1 = ((const uint32_t*)(h + (size_t)s1 * 128))[lane];
        f16x2 u0 = __builtin_bit_cast(f16x2, q0);
        f16x2 u1 = __builtin_bit_cast(f16x2, q1);
        float lo0 = (float)u0[0], hi0 = (float)u0[1];
        float lo1 = (float)u1[0], hi1 = (float)u1[1];
        for (int b = 0; b < 4; ++b) {
            float c0 = coef[r0 * 4 + b];
            float c1 = coef[r1 * 4 + b];
            acc[2 * b]     += c0 * lo0 + c1 * lo1;
            acc[2 * b + 1] += c0 * hi0 + c1 * hi1;
        }
    }
    if (i < e1) {
        int p0 = g.packed3[i];
        int s0 = p0 & 0xFFFFF, r0 = p0 >> 20;
        uint32_t q0 = ((const uint32_t*)(h + (size_t)s0 * 128))[lane];
        f16x2 u0 = __builtin_bit_cast(f16x2, q0);
        float lo0 = (float)u0[0], hi0 = (float)u0[1];
        for (int b = 0; b < 4; ++b) {
            float c0 = coef[r0 * 4 + b];
            acc[2 * b]     += c0 * lo0;
            acc[2 * b + 1] += c0 * hi0;
        }
    }
    _Float16* tb = T + (size_t)node * 512 + 2 * lane;
    for (int b = 0; b < 4; ++b) {
        f16x2 o; o[0] = (_Float16)acc[2 * b]; o[1] = (_Float16)acc[2 * b + 1];
        *(f16x2*)(tb + b * 128) = o;
    }
}

// ---- layer GEMM: out = [T | h] @ BT^T + bias (+relu), K=640, BM=128, 2x2 waves of 64x64 ----
struct GemmArgs {
    const _Float16* T;        // base; +v*Tvs
    const _Float16* hin[3];
    const _Float16* WT[3];    // [128][640]
    const float* bias[3];
    _Float16* hout;           // base; +v*hovs
    int M; int relu; size_t Tvs; size_t hovs;
};

__global__ __launch_bounds__(256) void gemm_layer(GemmArgs ga) {
    __shared__ _Float16 As[128 * AL];
    __shared__ _Float16 Bs[128 * AL];
    int v = blockIdx.y;
    const _Float16* Tb  = ga.T + (size_t)v * ga.Tvs;
    const _Float16* hin = ga.hin[v];
    const _Float16* BT  = ga.WT[v];
    const float* bias   = ga.bias[v];
    _Float16* out       = ga.hout + (size_t)v * ga.hovs;
    int M = ga.M;

    int tid = threadIdx.x;
    int m0 = blockIdx.x * 128;
    int wid = tid >> 6, lane = tid & 63;
    int wr = (wid >> 1) * 64;
    int wc = (wid & 1) * 64;
    int lm = lane & 15;
    int lk = (lane >> 4) * 8;

    f32x4 acc[4][4] = {};

    for (int kb = 0; kb < 5; ++kb) {
        const _Float16* Asrc; size_t astride;
        if (kb < 4) { Asrc = Tb + (size_t)kb * 128; astride = 512; }
        else        { Asrc = hin;                   astride = 128; }
        for (int q = 0; q < 8; ++q) {
            int li = tid + q * 256;
            int r = li >> 4;
            int c = (li & 15) << 3;
            int gr = m0 + r; if (gr >= M) gr = M - 1;
            *(f16x8*)(As + r * AL + c) = *(const f16x8*)(Asrc + (size_t)gr * astride + c);
        }
        for (int q = 0; q < 8; ++q) {
            int li = tid + q * 256;
            int r = li >> 4;
            int c = (li & 15) << 3;
            *(f16x8*)(Bs + r * AL + c) = *(const f16x8*)(BT + (size_t)r * 640 + kb * 128 + c);
        }
        __syncthreads();

        for (int ks = 0; ks < 4; ++ks) {
            f16x8 a[4], b[4];
            for (int mi = 0; mi < 4; ++mi)
                a[mi] = *(const f16x8*)(As + (wr + mi * 16 + lm) * AL + ks * 32 + lk);
            for (int ni = 0; ni < 4; ++ni)
                b[ni] = *(const f16x8*)(Bs + (wc + ni * 16 + lm) * AL + ks * 32 + lk);
            for (int mi = 0; mi < 4; ++mi)
                for (int ni = 0; ni < 4; ++ni)
                    acc[mi][ni] = __builtin_amdgcn_mfma_f32_16x16x32_f16(a[mi], b[ni], acc[mi][ni], 0, 0, 0);
        }
        __syncthreads();
    }

    int rbase = (lane >> 4) * 4;
    for (int mi = 0; mi < 4; ++mi) {
        for (int j = 0; j < 4; ++j) {
            int gr = m0 + wr + mi * 16 + rbase + j;
            if (gr >= M) continue;
            for (int ni = 0; ni < 4; ++ni) {
                int col = wc + ni * 16 + lm;
                float val = acc[mi][ni][j] + bias[col];
                if (ga.relu) val = fmaxf(val, 0.f);
                out[(size_t)gr * 128 + col] = (_Float16)val;
            }
        }
    }
}

// ---- fusion GEMM: out_f32 = sum_kb A[kb] @ BT_chunk + bias, BM=128 ----
struct FusArgs {
    const _Float16* A[3];     // K-chunks, each [M][128]
    const _Float16* BT;       // [128][bstride]
    const float* bias;        // optional
    float* out; int M; int nk; int accum; int bstride;
};

__global__ __launch_bounds__(256) void gemm_fusion(FusArgs fa) {
    __shared__ _Float16 As[128 * AL];
    __shared__ _Float16 Bs[128 * AL];
    int tid = threadIdx.x;
    int m0 = blockIdx.x * 128;
    int M = fa.M;
    int wid = tid >> 6, lane = tid & 63;
    int wr = (wid >> 1) * 64;
    int wc = (wid & 1) * 64;
    int lm = lane & 15;
    int lk = (lane >> 4) * 8;

    f32x4 acc[4][4] = {};

    for (int kb = 0; kb < fa.nk; ++kb) {
        const _Float16* Asrc = fa.A[kb];
        for (int q = 0; q < 8; ++q) {
            int li = tid + q * 256;
            int r = li >> 4;
            int c = (li & 15) << 3;
            int gr = m0 + r; if (gr >= M) gr = M - 1;
            *(f16x8*)(As + r * AL + c) = *(const f16x8*)(Asrc + (size_t)gr * 128 + c);
        }
        for (int q = 0; q < 8; ++q) {
            int li = tid + q * 256;
            int r = li >> 4;
            int c = (li & 15) << 3;
            *(f16x8*)(Bs + r * AL + c) = *(const f16x8*)(fa.BT + (size_t)r * fa.bstride + kb * 128 + c);
        }
        __syncthreads();

        for (int ks = 0; ks < 4; ++ks) {
            f16x8 a[4], b[4];
            for (int mi = 0; mi < 4; ++mi)
                a[mi] = *(const f16x8*)(As + (wr + mi * 16 + lm) * AL + ks * 32 + lk);
            for (int ni = 0; ni < 4; ++ni)
                b[ni] = *(const f16x8*)(Bs + (wc + ni * 16 + lm) * AL + ks * 32 + lk);
            for (int mi = 0; mi < 4; ++mi)
                for (int ni = 0; ni < 4; ++ni)
                    acc[mi][ni] = __builtin_amdgcn_mfma_f32_16x16x32_f16(a[mi], b[ni], acc[mi][ni], 0, 0, 0);
        }
        __syncthreads();
    }

    int rbase = (lane >> 4) * 4;
    for (int mi = 0; mi < 4; ++mi) {
        for (int j = 0; j < 4; ++j) {
            int gr = m0 + wr + mi * 16 + rbase + j;
            if (gr >= M) continue;
            for (int ni = 0; ni < 4; ++ni) {
                int col = wc + ni * 16 + lm;
                float val = acc[mi][ni][j];
                if (fa.bias) val += fa.bias[col];
                float* p = fa.out + (size_t)gr * 128 + col;
                if (fa.accum) *p += val; else *p = val;
            }
        }
    }
}

// ---------------- host launch ----------------
extern "C" void kernel_launch(void* const* d_in, const int* in_sizes, int n_in,
                              void* d_out, int out_size, void* d_ws, size_t ws_size,
                              hipStream_t stream) {
    const int D = 128;
    const int M = in_sizes[0] / D;

    struct ViewIn {
        const int *src, *dst, *rel;
        const float *bases1, *coef1, *loopw1, *bias1;
        const float *bases2, *coef2, *loopw2, *bias2;
        int E;
    } V[3];
    int idx = 1;
    for (int v = 0; v < 3; ++v) {
        V[v].src    = (const int*)d_in[idx + 0];
        V[v].dst    = (const int*)d_in[idx + 1];
        V[v].rel    = (const int*)d_in[idx + 2];
        V[v].bases1 = (const float*)d_in[idx + 3];
        V[v].coef1  = (const float*)d_in[idx + 4];
        V[v].loopw1 = (const float*)d_in[idx + 5];
        V[v].bias1  = (const float*)d_in[idx + 6];
        V[v].bases2 = (const float*)d_in[idx + 7];
        V[v].coef2  = (const float*)d_in[idx + 8];
        V[v].loopw2 = (const float*)d_in[idx + 9];
        V[v].bias2  = (const float*)d_in[idx + 10];
        V[v].E      = in_sizes[idx + 0];
        idx += 11;
    }
    const float* fusion_w = (const float*)d_in[idx];
    const float* fusion_b = (const float*)d_in[idx + 1];
    int Etot = V[0].E + V[1].E + V[2].E;

    // ---- workspace carve ----
    char* w = (char*)d_ws;
    auto alloc = [&](size_t bytes) -> char* {
        char* p = w; w += (bytes + 255) & ~(size_t)255; return p;
    };
    _Float16* nf16    = (_Float16*)alloc((size_t)M * 128 * 2);
    _Float16* wts     = (_Float16*)alloc((size_t)(6 * 81920 + 49152) * 2);
    int* deg3         = (int*)alloc((size_t)3 * M * 4);
    int* cur3         = (int*)alloc((size_t)3 * M * 4);
    int* bsum         = (int*)alloc(512);
    int* off3         = (int*)alloc(((size_t)3 * M + 1) * 4);
    int* packed3      = (int*)alloc((size_t)Etot * 4);

    size_t used = (size_t)(w - (char*)d_ws);
    size_t needB = ((size_t)M * 512 * 2 + 256) * 3 / 1   // T3 (with slack)
                 + ((size_t)M * 128 * 2 + 256) * 6;      // h1_3 + h2_3
    bool batched = (used + (size_t)3 * M * 512 * 2 + (size_t)6 * M * 128 * 2 + 4096) <= ws_size;
    (void)needB;

    _Float16 *T3, *h1b, *h2b;
    if (batched) {
        T3  = (_Float16*)alloc((size_t)3 * M * 512 * 2);
        h1b = (_Float16*)alloc((size_t)3 * M * 128 * 2);
        h2b = (_Float16*)alloc((size_t)3 * M * 128 * 2);
    } else {
        T3  = (_Float16*)alloc((size_t)M * 512 * 2);
        h1b = (_Float16*)alloc((size_t)M * 128 * 2);
        h2b = (_Float16*)alloc((size_t)M * 128 * 2);
    }

    // WT[v][l]: [128][640]; fusTcat: [128][384]
    _Float16 *WT[3][2];
    for (int v = 0; v < 3; ++v)
        for (int l = 0; l < 2; ++l)
            WT[v][l] = wts + (size_t)(v * 2 + l) * 81920;
    _Float16* fusTcat = wts + 6 * 81920;

    // ---- prep descriptors ----
    PrepArgs pa;
    int t = 0;
    for (int v = 0; v < 3; ++v) {
        const float* bases[2] = { V[v].bases1, V[v].bases2 };
        const float* loopw[2] = { V[v].loopw1, V[v].loopw2 };
        for (int l = 0; l < 2; ++l) {
            for (int b = 0; b < 4; ++b) {
                pa.d[t].src = bases[l] + (size_t)b * 16384;
                pa.d[t].dst = WT[v][l] + (size_t)b * 128;
                pa.d[t].dstride = 640; ++t;
            }
            pa.d[t].src = loopw[l];
            pa.d[t].dst = WT[v][l] + 512;
            pa.d[t].dstride = 640; ++t;
        }
    }
    for (int v = 0; v < 3; ++v) {
        pa.d[t].src = fusion_w + (size_t)v * 16384;
        pa.d[t].dst = fusTcat + (size_t)v * 128;
        pa.d[t].dstride = 384; ++t;
    }
    prep_weights<<<33, 256, 0, stream>>>(pa);

    int n4 = M * D / 4;
    f32_to_f16<<<(n4 + 255) / 256, 256, 0, stream>>>((const float*)d_in[0], nf16, n4);

    // ---- batched CSR build ----
    EdgeArgs ea;
    for (int v = 0; v < 3; ++v) {
        ea.src[v] = V[v].src; ea.dst[v] = V[v].dst; ea.rel[v] = V[v].rel; ea.E[v] = V[v].E;
    }
    ea.N = M;
    int n3 = 3 * M;
    zero_deg<<<(n3 + 255) / 256, 256, 0, stream>>>(deg3, n3);
    hist3<<<dim3(512, 3), 256, 0, stream>>>(ea, deg3);
    int nsb = (n3 + 2047) / 2048;
    scan1_kernel<<<nsb, 256, 0, stream>>>(deg3, off3, bsum, n3);
    scan2_kernel<<<nsb, 256, 0, stream>>>(off3, cur3, bsum, n3, Etot);
    scatter3<<<dim3(512, 3), 256, 0, stream>>>(ea, cur3, packed3);

    int ng  = (M + 3) / 4;
    int gxB = (M + 127) / 128;
    float* outF = (float*)d_out;
    size_t Tvs = (size_t)M * 512;
    size_t hvs = (size_t)M * 128;

    if (batched) {
        GatherArgs g1;
        g1.off3 = off3; g1.packed3 = packed3; g1.T = T3; g1.N = M; g1.Tvs = Tvs;
        for (int v = 0; v < 3; ++v) { g1.coef[v] = V[v].coef1; g1.h[v] = nf16; }
        gather3<<<dim3(ng, 3), 256, 0, stream>>>(g1);

        GemmArgs m1;
        m1.T = T3; m1.hout = h1b; m1.M = M; m1.relu = 1; m1.Tvs = Tvs; m1.hovs = hvs;
        for (int v = 0; v < 3; ++v) { m1.hin[v] = nf16; m1.WT[v] = WT[v][0]; m1.bias[v] = V[v].bias1; }
        gemm_layer<<<dim3(gxB, 3), 256, 0, stream>>>(m1);

        GatherArgs g2 = g1;
        for (int v = 0; v < 3; ++v) { g2.coef[v] = V[v].coef2; g2.h[v] = h1b + (size_t)v * hvs; }
        gather3<<<dim3(ng, 3), 256, 0, stream>>>(g2);

        GemmArgs m2;
        m2.T = T3; m2.hout = h2b; m2.M = M; m2.relu = 0; m2.Tvs = Tvs; m2.hovs = hvs;
        for (int v = 0; v < 3; ++v) { m2.hin[v] = h1b + (size_t)v * hvs; m2.WT[v] = WT[v][1]; m2.bias[v] = V[v].bias2; }
        gemm_layer<<<dim3(gxB, 3), 256, 0, stream>>>(m2);

        FusArgs fa;
        for (int v = 0; v < 3; ++v) fa.A[v] = h2b + (size_t)v * hvs;
        fa.BT = fusTcat; fa.bias = fusion_b; fa.out = outF;
        fa.M = M; fa.nk = 3; fa.accum = 0; fa.bstride = 384;
        gemm_fusion<<<gxB, 256, 0, stream>>>(fa);
    } else {
        for (int v = 0; v < 3; ++v) {
            GatherArgs g1;
            g1.off3 = off3 + (size_t)v * M; g1.packed3 = packed3; g1.T = T3; g1.N = M; g1.Tvs = 0;
            g1.coef[0] = V[v].coef1; g1.h[0] = nf16;
            g1.coef[1] = g1.coef[0]; g1.h[1] = g1.h[0];
            g1.coef[2] = g1.coef[0]; g1.h[2] = g1.h[0];
            gather3<<<dim3(ng, 1), 256, 0, stream>>>(g1);

            GemmArgs m1;
            m1.T = T3; m1.hout = h1b; m1.M = M; m1.relu = 1; m1.Tvs = 0; m1.hovs = 0;
            m1.hin[0] = nf16; m1.WT[0] = WT[v][0]; m1.bias[0] = V[v].bias1;
            m1.hin[1] = m1.hin[0]; m1.WT[1] = m1.WT[0]; m1.bias[1] = m1.bias[0];
            m1.hin[2] = m1.hin[0]; m1.WT[2] = m1.WT[0]; m1.bias[2] = m1.bias[0];
            gemm_layer<<<dim3(gxB, 1), 256, 0, stream>>>(m1);

            GatherArgs g2 = g1;
            g2.coef[0] = V[v].coef2; g2.h[0] = h1b;
            g2.coef[1] = g2.coef[0]; g2.h[1] = g2.h[0];
            g2.coef[2] = g2.coef[0]; g2.h[2] = g2.h[0];
            gather3<<<dim3(ng, 1), 256, 0, stream>>>(g2);

            GemmArgs m2;
            m2.T = T3; m2.hout = h2b; m2.M = M; m2.relu = 0; m2.Tvs = 0; m2.hovs = 0;
            m2.hin[0] = h1b; m2.WT[0] = WT[v][1]; m2.bias[0] = V[v].bias2;
            m2.hin[1] = m2.hin[0]; m2.WT[1] = m2.WT[0]; m2.bias[1] = m2.bias[0];
            m2.hin[2] = m2.hin[0]; m2.WT[2] = m2.WT[0]; m2.bias[2] = m2.bias[0];
            gemm_layer<<<dim3(gxB, 1), 256, 0, stream>>>(m2);

            FusArgs fa;
            fa.A[0] = h2b; fa.A[1] = fa.A[0]; fa.A[2] = fa.A[0];
            fa.BT = fusTcat + (size_t)v * 128; fa.bias = (v == 0) ? fusion_b : nullptr;
            fa.out = outF; fa.M = M; fa.nk = 1; fa.accum = (v != 0); fa.bstride = 384;
            gemm_fusion<<<gxB, 256, 0, stream>>>(fa);
        }
    }
}